// Round 6
// baseline (873.934 us; speedup 1.0000x reference)
//
#include <hip/hip_runtime.h>

// WaveNet on MI355X — round 6: single persistent kernel + DIY grid barrier.
//  - 256 blocks x 512 thr, 1 block/CU (122 KB LDS) -> all blocks co-resident; spin
//    barrier with agent-scope acq/rel atomics (counters zeroed by pack_kernel).
//  - skip partial sum (W1_l @ z_l) accumulated in registers (pacc) across layers:
//    z (288 MB) and u (32 MB) traffic + 11 launches eliminated.
//  - conv split a-pass/g-pass with bf16-packed tanh(a) stash to hold VGPR < 256.
//  - out GEMM fused at the end: D[t][o] orientation -> b128 otile writes ->
//    full-128B-line 1-KB wave stores.
// ws: hA 16 + hB 16 + packed weights ~0.62 MB + barrier counters.

#define T_LEN 32768
#define N_B 4
#define NBLK 256

typedef unsigned short u16;
typedef __attribute__((ext_vector_type(8))) short short8;
typedef __attribute__((ext_vector_type(4))) float f32x4;

#define MFMA16(a, b, c) __builtin_amdgcn_mfma_f32_16x16x32_bf16((a), (b), (c), 0, 0, 0)

__device__ __forceinline__ u16 bf16_rne(float f) {
    unsigned u = __float_as_uint(f);
    u += 0x7FFFu + ((u >> 16) & 1u);
    return (u16)(u >> 16);
}
__device__ __forceinline__ float bf16_to_f(u16 h) {
    return __uint_as_float(((unsigned)h) << 16);
}
__device__ __forceinline__ float fast_tanh(float x) {
    float e = __expf(2.f * x);
    return 1.f - 2.f * __builtin_amdgcn_rcpf(e + 1.f);
}
__device__ __forceinline__ float fast_sigmoid(float x) {
    return __builtin_amdgcn_rcpf(1.f + __expf(-x));
}

// grid barrier: all NBLK blocks co-resident (1 block/CU). Release add publishes
// prior h-writes (agent-scope wb); acquire load invalidates for halo reads.
__device__ __forceinline__ void gridbar(unsigned* c, unsigned n) {
    __syncthreads();
    if (threadIdx.x == 0) {
        __threadfence();
        __hip_atomic_fetch_add(c, 1u, __ATOMIC_RELEASE, __HIP_MEMORY_SCOPE_AGENT);
        while (__hip_atomic_load(c, __ATOMIC_ACQUIRE, __HIP_MEMORY_SCOPE_AGENT) < n)
            __builtin_amdgcn_s_sleep(4);
        __threadfence();
    }
    __syncthreads();
}

// ---- weight prepack (fp32->bf16, conv reordered to [l][o][k=tap*64+c]) + barrier zero ----
__global__ __launch_bounds__(256) void pack_kernel(
    const float* __restrict__ wc, const float* __restrict__ wo,
    const float* __restrict__ w1, const float* __restrict__ w2,
    u16* __restrict__ Wc, u16* __restrict__ Wo, u16* __restrict__ W1p, u16* __restrict__ W2p,
    unsigned* __restrict__ bar)
{
    int i = blockIdx.x * 256 + threadIdx.x;
    if (blockIdx.x == 0 && threadIdx.x < 16) bar[threadIdx.x] = 0u;
    if (i < 221184) {                       // 9*128*192 conv
        int l = i / 24576, rem = i % 24576;
        int o = rem / 192, k = rem % 192;
        int tap = k / 64, c = k % 64;
        Wc[i] = bf16_rne(wc[((l * 128 + o) * 64 + c) * 3 + tap]);
    } else if (i < 258048) {                // 9*64*64 residual 1x1
        int j = i - 221184; Wo[j] = bf16_rne(wo[j]);
    } else if (i < 294912) {                // 64*576 out1 [o][k]
        int j = i - 258048; W1p[j] = bf16_rne(w1[j]);
    } else if (i < 311296) {                // 256*64 out2 [o][k]
        int j = i - 294912; W2p[j] = bf16_rne(w2[j]);
    }
}

// ---- the whole net: input -> 9 dilated layers (+reg skip accum) -> u -> out ----
__global__ __launch_bounds__(512, 2) void wavenet_kernel(
    const float* __restrict__ x, const float* __restrict__ wi, const float* __restrict__ bi,
    const u16* __restrict__ Wc, const u16* __restrict__ Wo,
    const u16* __restrict__ W1p, const u16* __restrict__ W2p,
    const float* __restrict__ bc, const float* __restrict__ bo,
    const float* __restrict__ b1, const float* __restrict__ b2,
    u16* __restrict__ hA, u16* __restrict__ hB,
    float* __restrict__ out, unsigned* __restrict__ bar)
{
    // layer phase: wshC 48K | wshO 8K | wshS 8K | zt 18K   (82 KB)
    // out  phase: w2sh 32K | otile 72K | ut 18K            (122 KB)
    __shared__ u16 smem[62464];
    u16* wshC = smem;                    // 24576 u16
    u16* wshO = smem + 24576;            // 4096
    u16* wshS = smem + 28672;            // 4096
    u16* ztb  = smem + 32768;            // 9216 (8 waves x 16 x 72)
    u16* w2sh = smem;                    // 16384 (out phase)
    float* otile = (float*)(smem + 16384);  // 8 x 64 x 36 f32
    u16* utb  = smem + 53248;            // 9216

    const int tid = threadIdx.x;
    const int wv = tid >> 6, lane = tid & 63;
    const int quad = lane >> 4, col = lane & 15;
    const int b = blockIdx.x >> 6;               // batch
    const int t0b = (blockIdx.x & 63) * 512;     // block's t range
    const f32x4 Z = {0.f, 0.f, 0.f, 0.f};

    // ---- phase 0: input 1x1 conv + tanh -> hA (1 t per thread) ----
    {
        const int t = t0b + tid;
        const float xv = x[b * T_LEN + t];
        u16* dst = hA + ((size_t)b * T_LEN + t) * 64;
        #pragma unroll
        for (int c8 = 0; c8 < 8; ++c8) {
            unsigned w[4];
            #pragma unroll
            for (int p2 = 0; p2 < 4; ++p2) {
                int c = c8 * 8 + p2 * 2;
                unsigned lo = bf16_rne(fast_tanh(xv * wi[c]     + bi[c]));
                unsigned hi = bf16_rne(fast_tanh(xv * wi[c + 1] + bi[c + 1]));
                w[p2] = lo | (hi << 16);
            }
            *(uint4*)(dst + c8 * 8) = make_uint4(w[0], w[1], w[2], w[3]);
        }
    }
    gridbar(bar, NBLK);

    const u16* hIn = hA;
    u16* hOut = hB;
    u16* zt = ztb + wv * (16 * 72);
    const int t0w = t0b + wv * 64;

    f32x4 pacc[4][4];   // skip partial sums, live across all layers
    #pragma unroll
    for (int c = 0; c < 4; ++c)
        #pragma unroll
        for (int j = 0; j < 4; ++j) pacc[c][j] = Z;

    #pragma unroll 1
    for (int l = 0; l < 9; ++l) {
        const int dil = 1 << l;
        const u16* wl  = Wc + l * (128 * 192);
        const u16* wol = Wo + l * (64 * 64);

        #pragma unroll
        for (int rep = 0; rep < 6; ++rep) {            // 3072 conv frags
            int i = rep * 512 + tid;
            int o = i / 24, m = i % 24, ks = m >> 2, q = m & 3;
            *(short8*)&wshC[((ks * 128 + o) * 4 + q) * 8] =
                *(const short8*)(wl + o * 192 + ks * 32 + q * 8);
        }
        {                                              // res + skip frags
            int r = tid >> 3, m = tid & 7, ks = m >> 2, q = m & 3;
            *(short8*)&wshO[((ks * 64 + r) * 4 + q) * 8] =
                *(const short8*)(wol + r * 64 + ks * 32 + q * 8);
            *(short8*)&wshS[((ks * 64 + r) * 4 + q) * 8] =
                *(const short8*)(W1p + r * 576 + l * 64 + ks * 32 + q * 8);
        }
        __syncthreads();

        const float* bcl = bc + l * 128;
        float ba[4], bg[4], bo_[4];
        #pragma unroll
        for (int j = 0; j < 4; ++j) {
            ba[j]  = bcl[j * 16 + col];
            bg[j]  = bcl[64 + j * 16 + col];
            bo_[j] = bo[l * 64 + j * 16 + col];
        }

        f32x4 acc[4][4];
        unsigned ta[4][4][2];   // tanh(a) stash, bf16-packed

        // --- conv pass A (o = 0..63): K = 192 ---
        #pragma unroll
        for (int c = 0; c < 4; ++c)
            #pragma unroll
            for (int j = 0; j < 4; ++j) acc[c][j] = Z;
        #pragma unroll
        for (int ks = 0; ks < 6; ++ks) {
            const int back = (2 - (ks >> 1)) * dil;    // causal: w[tap] hits t-(2-tap)*d
            const int cb = (ks & 1) * 32 + quad * 8;
            short8 af[4];
            #pragma unroll
            for (int m = 0; m < 4; ++m) {
                const int tt = t0w + m * 16 + col - back;
                af[m] = short8{};
                if (tt >= 0)
                    af[m] = *(const short8*)(hIn + (((size_t)b * T_LEN + tt) * 64 + cb));
            }
            #pragma unroll
            for (int j = 0; j < 4; ++j) {
                short8 wf = *(const short8*)&wshC[((ks * 128 + j * 16 + col) * 4 + quad) * 8];
                #pragma unroll
                for (int m = 0; m < 4; ++m) acc[m][j] = MFMA16(af[m], wf, acc[m][j]);
            }
        }
        #pragma unroll
        for (int c = 0; c < 4; ++c)
            #pragma unroll
            for (int j = 0; j < 4; ++j) {
                unsigned p0 = (unsigned)bf16_rne(fast_tanh(acc[c][j][0] + ba[j])) |
                              ((unsigned)bf16_rne(fast_tanh(acc[c][j][1] + ba[j])) << 16);
                unsigned p1 = (unsigned)bf16_rne(fast_tanh(acc[c][j][2] + ba[j])) |
                              ((unsigned)bf16_rne(fast_tanh(acc[c][j][3] + ba[j])) << 16);
                ta[c][j][0] = p0; ta[c][j][1] = p1;
            }

        // --- conv pass G (o = 64..127) ---
        #pragma unroll
        for (int c = 0; c < 4; ++c)
            #pragma unroll
            for (int j = 0; j < 4; ++j) acc[c][j] = Z;
        #pragma unroll
        for (int ks = 0; ks < 6; ++ks) {
            const int back = (2 - (ks >> 1)) * dil;
            const int cb = (ks & 1) * 32 + quad * 8;
            short8 af[4];
            #pragma unroll
            for (int m = 0; m < 4; ++m) {
                const int tt = t0w + m * 16 + col - back;
                af[m] = short8{};
                if (tt >= 0)
                    af[m] = *(const short8*)(hIn + (((size_t)b * T_LEN + tt) * 64 + cb));
            }
            #pragma unroll
            for (int j = 0; j < 4; ++j) {
                short8 wf = *(const short8*)&wshC[((ks * 128 + 64 + j * 16 + col) * 4 + quad) * 8];
                #pragma unroll
                for (int m = 0; m < 4; ++m) acc[m][j] = MFMA16(af[m], wf, acc[m][j]);
            }
        }

        // --- per 16-t chunk: gate -> zt -> res/skip GEMM -> h update ---
        #pragma unroll
        for (int c = 0; c < 4; ++c) {
            #pragma unroll
            for (int j = 0; j < 4; ++j)
                #pragma unroll
                for (int r = 0; r < 4; ++r) {
                    float av = bf16_to_f((u16)(ta[c][j][r >> 1] >> ((r & 1) * 16)));
                    float g  = acc[c][j][r] + bg[j];
                    zt[(quad * 4 + r) * 72 + j * 16 + col] =
                        bf16_rne(av * fast_sigmoid(g));
                }
            f32x4 hacc[4] = {Z, Z, Z, Z};
            #pragma unroll
            for (int ks = 0; ks < 2; ++ks) {
                short8 afz = *(const short8*)&zt[col * 72 + ks * 32 + quad * 8];
                #pragma unroll
                for (int j = 0; j < 4; ++j) {
                    if (l < 8) {
                        short8 wf = *(const short8*)&wshO[((ks * 64 + j * 16 + col) * 4 + quad) * 8];
                        hacc[j] = MFMA16(afz, wf, hacc[j]);
                    }
                    short8 sf = *(const short8*)&wshS[((ks * 64 + j * 16 + col) * 4 + quad) * 8];
                    pacc[c][j] = MFMA16(afz, sf, pacc[c][j]);
                }
            }
            if (l < 8) {
                #pragma unroll
                for (int j = 0; j < 4; ++j)
                    #pragma unroll
                    for (int r = 0; r < 4; ++r)
                        zt[(quad * 4 + r) * 72 + j * 16 + col] = bf16_rne(hacc[j][r] + bo_[j]);
                const int zr = lane >> 2, zc = (lane & 3) * 16;
                const size_t hb = ((size_t)b * T_LEN + t0w + c * 16 + zr) * 64 + zc;
                #pragma unroll
                for (int s = 0; s < 2; ++s) {
                    short8 hv = *(const short8*)(hIn + hb + s * 8);
                    short8 rv = *(const short8*)&zt[zr * 72 + zc + s * 8];
                    short8 ov;
                    #pragma unroll
                    for (int e = 0; e < 8; ++e)
                        ov[e] = (short)bf16_rne(bf16_to_f((u16)hv[e]) + bf16_to_f((u16)rv[e]));
                    *(short8*)(hOut + hb + s * 8) = ov;
                }
            }
        }
        if (l < 8) {
            u16* tmp = hOut; hOut = (u16*)hIn; hIn = tmp;   // ping-pong
            gridbar(bar + 1 + l, NBLK);                     // publish h for halos
        }
    }

    // ---- out phase: u = tanh(pacc + b1); out = W2 @ u + b2 (D[t][o] orientation) ----
    __syncthreads();                       // all waves done with layer LDS
    #pragma unroll
    for (int rep = 0; rep < 4; ++rep) {    // stage W2 frags (2048 x 16B)
        int i = rep * 512 + tid;
        int o = (i >> 2) & 255, ks = i >> 10, q = i & 3;
        *(short8*)&w2sh[((ks * 256 + o) * 4 + q) * 8] =
            *(const short8*)(W2p + o * 64 + ks * 32 + q * 8);
    }
    __syncthreads();

    float b1v[4];
    #pragma unroll
    for (int j = 0; j < 4; ++j) b1v[j] = b1[j * 16 + col];
    u16* ut = utb + wv * (16 * 72);
    float* ot = otile + wv * (64 * 36);

    #pragma unroll 1
    for (int cp = 0; cp < 2; ++cp) {
        short8 uf[2][2];
        #pragma unroll
        for (int ci = 0; ci < 2; ++ci) {
            const int c = cp * 2 + ci;
            #pragma unroll
            for (int j = 0; j < 4; ++j)
                #pragma unroll
                for (int r = 0; r < 4; ++r)
                    ut[(quad * 4 + r) * 72 + j * 16 + col] =
                        bf16_rne(fast_tanh(pacc[c][j][r] + b1v[j]));
            uf[ci][0] = *(const short8*)&ut[col * 72 + quad * 8];
            uf[ci][1] = *(const short8*)&ut[col * 72 + 32 + quad * 8];
        }
        f32x4 oacc[2][16];
        #pragma unroll
        for (int ci = 0; ci < 2; ++ci)
            #pragma unroll
            for (int mm = 0; mm < 16; ++mm) oacc[ci][mm] = Z;
        #pragma unroll
        for (int mm = 0; mm < 16; ++mm) {     // A = u (m=t), B = W2 (n=o) -> D[t][o]
            short8 w0 = *(const short8*)&w2sh[((mm * 16 + col) * 4 + quad) * 8];
            short8 w1f = *(const short8*)&w2sh[((256 + mm * 16 + col) * 4 + quad) * 8];
            #pragma unroll
            for (int ci = 0; ci < 2; ++ci) {
                oacc[ci][mm] = MFMA16(uf[ci][0], w0, oacc[ci][mm]);
                oacc[ci][mm] = MFMA16(uf[ci][1], w1f, oacc[ci][mm]);
            }
        }
        #pragma unroll
        for (int s = 0; s < 4; ++s) {         // 64-o slices -> full-line stores
            #pragma unroll
            for (int m4 = 0; m4 < 4; ++m4) {
                const int mm = s * 4 + m4;
                const float bb = b2[s * 64 + m4 * 16 + col];
                #pragma unroll
                for (int ci = 0; ci < 2; ++ci) {
                    f32x4 v = {oacc[ci][mm][0] + bb, oacc[ci][mm][1] + bb,
                               oacc[ci][mm][2] + bb, oacc[ci][mm][3] + bb};
                    *(f32x4*)&ot[(m4 * 16 + col) * 36 + ci * 16 + quad * 4] = v;
                }
            }
            const int orow = lane >> 3, tof = (lane & 7) * 4;
            #pragma unroll
            for (int i8 = 0; i8 < 8; ++i8) {
                const int ol = i8 * 8 + orow;
                f32x4 vv = *(const f32x4*)&ot[ol * 36 + tof];
                *(f32x4*)(out + ((size_t)b * 256 + s * 64 + ol) * T_LEN +
                          t0w + cp * 32 + tof) = vv;
            }
        }
    }
}

extern "C" void kernel_launch(void* const* d_in, const int* in_sizes, int n_in,
                              void* d_out, int out_size, void* d_ws, size_t ws_size,
                              hipStream_t stream)
{
    const float* x  = (const float*)d_in[0];
    const float* wi = (const float*)d_in[1];
    const float* bi = (const float*)d_in[2];
    const float* wc = (const float*)d_in[3];
    const float* bc = (const float*)d_in[4];
    const float* wo = (const float*)d_in[5];
    const float* bo = (const float*)d_in[6];
    const float* w1 = (const float*)d_in[7];
    const float* b1 = (const float*)d_in[8];
    const float* w2 = (const float*)d_in[9];
    const float* b2 = (const float*)d_in[10];
    float* out = (float*)d_out;

    char* ws = (char*)d_ws;
    const size_t HBYTES = (size_t)N_B * T_LEN * 64 * 2;   // 16 MB
    u16* hA = (u16*)ws;
    u16* hB = (u16*)(ws + HBYTES);
    size_t off = 2 * HBYTES;
    u16* Wc  = (u16*)(ws + off); off += (size_t)9 * 128 * 192 * 2;
    u16* Wo  = (u16*)(ws + off); off += (size_t)9 * 64 * 64 * 2;
    u16* W1p = (u16*)(ws + off); off += (size_t)64 * 576 * 2;
    u16* W2p = (u16*)(ws + off); off += (size_t)256 * 64 * 2;
    unsigned* bar = (unsigned*)(ws + off); off += 64;
    if (ws_size < off) return;   // needs ~34 MB of workspace

    pack_kernel<<<1216, 256, 0, stream>>>(wc, wo, w1, w2, Wc, Wo, W1p, W2p, bar);
    wavenet_kernel<<<NBLK, 512, 0, stream>>>(x, wi, bi, Wc, Wo, W1p, W2p,
                                             bc, bo, b1, b2, hA, hB, out, bar);
}